// Round 2
// baseline (546.864 us; speedup 1.0000x reference)
//
#include <hip/hip_runtime.h>
#include <hip/hip_bf16.h>
#include <math.h>

#define M_TOT 16384   // B*S
#define D_DIM 4096
#define H_DIM 128
#define E_DIM 8

// ---------------- task router: layer1 split-K ----------------
// grid: 4 batches * 32 k-chunks = 128 blocks, 128 threads (one per h-column)
__global__ __launch_bounds__(128)
void task1_kernel(const float* __restrict__ tp, const float* __restrict__ TW1,
                  float* __restrict__ th) {
  int b = blockIdx.x >> 5;
  int kq = blockIdx.x & 31;
  int j = threadIdx.x;
  int k0 = kq * 128;
  __shared__ float xs[128];
  xs[j] = tp[b * D_DIM + k0 + j];
  __syncthreads();
  float acc = 0.f;
  #pragma unroll 8
  for (int k = 0; k < 128; ++k)
    acc += xs[k] * TW1[(size_t)(k0 + k) * H_DIM + j];  // coalesced across j
  th[((size_t)b * 32 + kq) * 128 + j] = acc;
}

// ---------------- task router: reduce + layer2 + softmax ----------------
// grid: 4 blocks, 128 threads
__global__ __launch_bounds__(128)
void task2_kernel(const float* __restrict__ th, const float* __restrict__ Tb1,
                  const float* __restrict__ TW2, const float* __restrict__ Tb2,
                  const float* __restrict__ alpha,
                  float* __restrict__ ta, float* __restrict__ onema) {
  int b = blockIdx.x;
  int j = threadIdx.x;
  float acc = 0.f;
  for (int kq = 0; kq < 32; ++kq) acc += th[((size_t)b * 32 + kq) * 128 + j];
  float h = fmaxf(acc + Tb1[j], 0.f);
  __shared__ float hsm[128];
  __shared__ float ysm[8];
  hsm[j] = h;
  __syncthreads();
  if (j < 8) {
    float y = Tb2[j];
    for (int q = 0; q < 128; ++q) y += hsm[q] * TW2[q * E_DIM + j];
    ysm[j] = y;
  }
  __syncthreads();
  if (j == 0) {
    float a = 1.f / (1.f + expf(-alpha[0]));
    float m = ysm[0];
    for (int e = 1; e < 8; ++e) m = fmaxf(m, ysm[e]);
    float ex[8]; float s = 0.f;
    for (int e = 0; e < 8; ++e) { ex[e] = expf(ysm[e] - m); s += ex[e]; }
    float inv = 1.f / s;
    for (int e = 0; e < 8; ++e) ta[b * 8 + e] = a * ex[e] * inv;  // a * task_w
    if (b == 0) *onema = 1.f - a;
  }
}

// ---------------- main GEMM: h_partial = A[rows, kchunk] @ W1[kchunk, 128] ----
// BM=128 rows, BN=128 (= all of H), BK=32, 256 threads, 8x8 per thread.
// grid: (128 row-groups, KS split-K)
#define BM 128
#define BK 32

__global__ __launch_bounds__(256, 2)
void gemm1_kernel(const float* __restrict__ A, const float* __restrict__ W1,
                  float* __restrict__ P, int kchunk) {
  __shared__ float As[BK][132];   // [k][row], +4 pad keeps float4 align, tames write conflicts
  __shared__ float Bs[BK][128];   // [k][col]
  const int tid = threadIdx.x;
  const int rg = blockIdx.x;
  const int k0 = blockIdx.y * kchunk;
  const int tr = tid >> 4;     // 0..15 -> rows tr*8..tr*8+7
  const int tc = tid & 15;     // 0..15 -> cols tc*8..tc*8+7
  const float* Ab = A + (size_t)rg * BM * D_DIM + k0;
  const float* Wb = W1 + (size_t)k0 * H_DIM;

  float acc[8][8];
  #pragma unroll
  for (int i = 0; i < 8; ++i)
    #pragma unroll
    for (int jj = 0; jj < 8; ++jj) acc[i][jj] = 0.f;

  float4 va[4], vb[4];
  #pragma unroll
  for (int l = 0; l < 4; ++l) {   // prologue loads for tile 0
    int fi = l * 256 + tid;
    int row = fi >> 3, kq = fi & 7;                 // 8 f4 per row -> 128B/row coalesced
    va[l] = *(const float4*)(Ab + (size_t)row * D_DIM + kq * 4);
    int kb = fi >> 5, col = (fi & 31) * 4;
    vb[l] = *(const float4*)(Wb + (size_t)kb * H_DIM + col);
  }
  const int nt = kchunk / BK;
  for (int kt = 0; kt < nt; ++kt) {
    #pragma unroll
    for (int l = 0; l < 4; ++l) {                   // LDS write (A transposed)
      int fi = l * 256 + tid;
      int row = fi >> 3, kq = fi & 7;
      As[kq * 4 + 0][row] = va[l].x;
      As[kq * 4 + 1][row] = va[l].y;
      As[kq * 4 + 2][row] = va[l].z;
      As[kq * 4 + 3][row] = va[l].w;
      int kb = fi >> 5, col = (fi & 31) * 4;
      *(float4*)&Bs[kb][col] = vb[l];
    }
    __syncthreads();
    if (kt + 1 < nt) {                              // prefetch next tile into regs
      int koff = (kt + 1) * BK;
      #pragma unroll
      for (int l = 0; l < 4; ++l) {
        int fi = l * 256 + tid;
        int row = fi >> 3, kq = fi & 7;
        va[l] = *(const float4*)(Ab + (size_t)row * D_DIM + koff + kq * 4);
        int kb = fi >> 5, col = (fi & 31) * 4;
        vb[l] = *(const float4*)(Wb + (size_t)(koff + kb) * H_DIM + col);
      }
    }
    #pragma unroll 8
    for (int kk = 0; kk < BK; ++kk) {
      float a0[8], b0[8];
      *(float4*)&a0[0] = *(const float4*)&As[kk][tr * 8];
      *(float4*)&a0[4] = *(const float4*)&As[kk][tr * 8 + 4];
      *(float4*)&b0[0] = *(const float4*)&Bs[kk][tc * 8];
      *(float4*)&b0[4] = *(const float4*)&Bs[kk][tc * 8 + 4];
      #pragma unroll
      for (int i = 0; i < 8; ++i)
        #pragma unroll
        for (int jj = 0; jj < 8; ++jj)
          acc[i][jj] += a0[i] * b0[jj];             // contracts to v_fmac_f32
    }
    __syncthreads();
  }
  float* Pb = P + ((size_t)blockIdx.y * M_TOT + (size_t)rg * BM) * H_DIM;
  #pragma unroll
  for (int i = 0; i < 8; ++i) {
    size_t row = (size_t)(tr * 8 + i);
    *(float4*)&Pb[row * H_DIM + tc * 8]     = *(float4*)&acc[i][0];
    *(float4*)&Pb[row * H_DIM + tc * 8 + 4] = *(float4*)&acc[i][4];
  }
}

// ---------------- fused tail: reduce partials + bias/relu + layer2 + routing --
// grid: 256 blocks x 256 threads, 64 rows per block
__global__ __launch_bounds__(256)
void tail_kernel(const float* __restrict__ P, int KS,
                 const float* __restrict__ b1, const float* __restrict__ W2,
                 const float* __restrict__ b2, const float* __restrict__ ta,
                 const float* __restrict__ onema, float* __restrict__ out) {
  __shared__ float hs[64][129];   // +1 pad: conflict-free row reads in layer2
  __shared__ float W2s[128][8];
  __shared__ float ys[64][9];
  const int tid = threadIdx.x;
  const int r0 = blockIdx.x * 64;
  if (tid < 128) {
    *(float4*)&W2s[tid][0] = *(const float4*)&W2[tid * 8];
    *(float4*)&W2s[tid][4] = *(const float4*)&W2[tid * 8 + 4];
  }
  #pragma unroll
  for (int q = 0; q < 8; ++q) {
    int fi = q * 256 + tid;       // float4 index, 2048 total
    int row = fi >> 5;            // 0..63
    int c = (fi & 31) * 4;        // 0..124
    const float* p0 = P + (size_t)(r0 + row) * H_DIM + c;
    float4 s = *(const float4*)p0;
    for (int l = 1; l < KS; ++l) {
      const float4 v = *(const float4*)(p0 + (size_t)l * M_TOT * H_DIM);
      s.x += v.x; s.y += v.y; s.z += v.z; s.w += v.w;
    }
    const float4 bb = *(const float4*)&b1[c];
    hs[row][c + 0] = fmaxf(s.x + bb.x, 0.f);
    hs[row][c + 1] = fmaxf(s.y + bb.y, 0.f);
    hs[row][c + 2] = fmaxf(s.z + bb.z, 0.f);
    hs[row][c + 3] = fmaxf(s.w + bb.w, 0.f);
  }
  __syncthreads();
  {
    int r = tid >> 2;             // 0..63
    int e0 = (tid & 3) * 2;       // 0,2,4,6
    float y0 = b2[e0], y1 = b2[e0 + 1];
    #pragma unroll 8
    for (int j = 0; j < 128; ++j) {
      float hv = hs[r][j];
      y0 += hv * W2s[j][e0];
      y1 += hv * W2s[j][e0 + 1];
    }
    ys[r][e0] = y0;
    ys[r][e0 + 1] = y1;
  }
  __syncthreads();
  if (tid < 64) {
    int r = tid;
    int grow = r0 + r;
    int b = grow >> 12;           // 4096 rows per batch
    float y[8];
    #pragma unroll
    for (int e = 0; e < 8; ++e) y[e] = ys[r][e];
    float m = y[0];
    #pragma unroll
    for (int e = 1; e < 8; ++e) m = fmaxf(m, y[e]);
    float ex[8], ssum = 0.f;
    #pragma unroll
    for (int e = 0; e < 8; ++e) { ex[e] = expf(y[e] - m); ssum += ex[e]; }
    float inv = 1.f / ssum;
    float oma = *onema;
    float rt[8];
    #pragma unroll
    for (int e = 0; e < 8; ++e) rt[e] = oma * ex[e] * inv + ta[b * 8 + e];
    // top-2: strict '>' keeps lowest index on ties, matching lax.top_k
    int i1 = 0; float m1 = rt[0];
    #pragma unroll
    for (int e = 1; e < 8; ++e) if (rt[e] > m1) { m1 = rt[e]; i1 = e; }
    int i2 = -1; float m2 = -3.4e38f;
    #pragma unroll
    for (int e = 0; e < 8; ++e) if (e != i1 && rt[e] > m2) { m2 = rt[e]; i2 = e; }
    // masked softmax: kept -> exp(rt-m1)/Z, masked -> exactly 0 (exp(min-m1) underflows)
    float e2 = expf(m2 - m1);
    float Z = 1.f + e2;
    float o[8];
    #pragma unroll
    for (int e = 0; e < 8; ++e)
      o[e] = (e == i1) ? (1.f / Z) : ((e == i2) ? (e2 / Z) : 0.f);
    float4* op = (float4*)(out + (size_t)grow * 8);
    op[0] = make_float4(o[0], o[1], o[2], o[3]);
    op[1] = make_float4(o[4], o[5], o[6], o[7]);
  }
}

extern "C" void kernel_launch(void* const* d_in, const int* in_sizes, int n_in,
                              void* d_out, int out_size, void* d_ws, size_t ws_size,
                              hipStream_t stream) {
  const float* hidden = (const float*)d_in[0];
  const float* taskp  = (const float*)d_in[1];
  const float* W1     = (const float*)d_in[2];
  const float* b1     = (const float*)d_in[3];
  const float* W2     = (const float*)d_in[4];
  const float* b2     = (const float*)d_in[5];
  const float* TW1    = (const float*)d_in[6];
  const float* Tb1    = (const float*)d_in[7];
  const float* TW2    = (const float*)d_in[8];
  const float* Tb2    = (const float*)d_in[9];
  const float* alpha  = (const float*)d_in[10];
  float* out = (float*)d_out;

  char* ws = (char*)d_ws;
  float* th    = (float*)ws;                  // 4*32*128 floats = 64 KiB
  float* ta    = (float*)(ws + 65536);        // 32 floats (a * task_w)
  float* onema = (float*)(ws + 65536 + 128);  // 1 float (1 - a)
  float* P     = (float*)(ws + 131072);       // KS * 16384 * 128 floats

  const size_t layer_bytes = (size_t)M_TOT * H_DIM * 4;
  int KS = 4;
  if (ws_size < 131072 + 4 * layer_bytes) KS = 2;
  if (ws_size < 131072 + 2 * layer_bytes) KS = 1;
  int kchunk = D_DIM / KS;

  task1_kernel<<<128, 128, 0, stream>>>(taskp, TW1, th);
  task2_kernel<<<4, 128, 0, stream>>>(th, Tb1, TW2, Tb2, alpha, ta, onema);
  dim3 g1(M_TOT / BM, KS);
  gemm1_kernel<<<g1, 256, 0, stream>>>(hidden, W1, P, kchunk);
  tail_kernel<<<M_TOT / 64, 256, 0, stream>>>(P, KS, b1, W2, b2, ta, onema, out);
}